// Round 3
// baseline (85.146 us; speedup 1.0000x reference)
//
#include <hip/hip_runtime.h>
#include <hip/hip_bf16.h>

#define NBATCH 8
#define BROWS 256
#define KDIM 512
#define HIDD 512
#define GDIM 2048
#define KSTEP 64
#define NIT (KDIM / KSTEP)

typedef float f32x4 __attribute__((ext_vector_type(4)));
typedef __bf16 bf16x8 __attribute__((ext_vector_type(8)));

__device__ __forceinline__ unsigned fenc(float f) {
    unsigned u = __float_as_uint(f);
    return (u & 0x80000000u) ? ~u : (u | 0x80000000u);
}
__device__ __forceinline__ float fdec(unsigned e) {
    unsigned u = (e & 0x80000000u) ? (e & 0x7fffffffu) : ~e;
    return __uint_as_float(u);
}
__device__ __forceinline__ unsigned umaxu(unsigned a, unsigned b) { return a > b ? a : b; }

// quant(pact(x,a), 8, a)  -- all a's are powers of 2 so /a, *a are exact
__device__ __forceinline__ float qpact(float x, float a) {
    float ax = fabsf(x);
    float p  = copysignf(0.5f * (ax - fabsf(ax - a) + a), x);
    float x01 = p / a;
    x01 = fminf(fmaxf(x01, -0.9921875f), 0.9921875f);
    return (rintf(x01 * 128.f) * 0.0078125f) * a;
}
// quant(x, 8, 1.0)
__device__ __forceinline__ float q1(float x) {
    float x01 = fminf(fmaxf(x, -0.9921875f), 0.9921875f);
    return rintf(x01 * 128.f) * 0.0078125f;
}
__device__ __forceinline__ float sigmf(float x) { return 1.0f / (1.0f + expf(-x)); }

__global__ void k_init(unsigned* m) { if (threadIdx.x < 4) m[threadIdx.x] = 0u; }

__global__ void k_max(const float* __restrict__ w_ih, const float* __restrict__ w_hh,
                      const float* __restrict__ b_ih, const float* __restrict__ b_hh,
                      unsigned* __restrict__ omax) {
    int which = blockIdx.y;
    const float* src = which == 0 ? w_ih : which == 1 ? w_hh : which == 2 ? b_ih : b_hh;
    int n4 = (which < 2 ? NBATCH * KDIM * GDIM : NBATCH * GDIM) >> 2;
    unsigned best = 0u;
    int stride = gridDim.x * blockDim.x;
    for (int i = blockIdx.x * blockDim.x + threadIdx.x; i < n4; i += stride) {
        float4 v = ((const float4*)src)[i];
        best = umaxu(best, fenc(v.x)); best = umaxu(best, fenc(v.y));
        best = umaxu(best, fenc(v.z)); best = umaxu(best, fenc(v.w));
    }
    #pragma unroll
    for (int off = 32; off > 0; off >>= 1)
        best = umaxu(best, (unsigned)__shfl_down((int)best, off, 64));
    __shared__ unsigned red[4];
    int lane = threadIdx.x & 63, wv = threadIdx.x >> 6;
    if (lane == 0) red[wv] = best;
    __syncthreads();
    if (threadIdx.x == 0) {
        unsigned b2 = umaxu(umaxu(red[0], red[1]), umaxu(red[2], red[3]));
        atomicMax(&omax[which], b2);
    }
}

__global__ void k_prep(const float* __restrict__ input, const float* __restrict__ hx,
                       const float* __restrict__ bih, const float* __restrict__ bhh,
                       const float* __restrict__ nbih, const float* __restrict__ nbhh,
                       const float* __restrict__ a1, const unsigned* __restrict__ maxes,
                       __hip_bfloat16* __restrict__ xqh, __hip_bfloat16* __restrict__ hxh,
                       __hip_bfloat16* __restrict__ hxl, float* __restrict__ bias_comb) {
    const int NX = NBATCH * BROWS * KDIM;
    const int NH = NBATCH * BROWS * HIDD;
    const int NBC = NBATCH * GDIM;
    int total = NX + NH + NBC;
    int stride = gridDim.x * blockDim.x;
    for (int i = blockIdx.x * blockDim.x + threadIdx.x; i < total; i += stride) {
        if (i < NX) {
            int nb = i >> 17;              // /(256*512)
            int rem = i & 131071;
            float v = qpact(input[rem], a1[nb]);
            xqh[i] = __float2bfloat16(v);  // exact: integers <=127 for a1=128
        } else if (i < NX + NH) {
            int j = i - NX;
            float h = hx[j];
            __hip_bfloat16 hi = __float2bfloat16(h);
            hxh[j] = hi;
            hxl[j] = __float2bfloat16(h - __bfloat162float(hi));
        } else {
            int j = i - NX - NH;
            float mb_ih = fdec(maxes[2]);
            float mb_hh = fdec(maxes[3]);
            bias_comb[j] = q1(bih[j]) + (nbih[j] * mb_ih) * 0.05f
                         + q1(bhh[j]) + (nbhh[j] * mb_hh) * 0.05f;
        }
    }
}

__global__ __launch_bounds__(1024, 1) void k_gemm(
    const float* __restrict__ w_ih, const float* __restrict__ w_hh,
    const float* __restrict__ n_ih, const float* __restrict__ n_hh,
    const __hip_bfloat16* __restrict__ xqh, const __hip_bfloat16* __restrict__ hxh,
    const __hip_bfloat16* __restrict__ hxl,
    const float* __restrict__ bias_comb, const float* __restrict__ cx,
    const float* __restrict__ a3, const float* __restrict__ a4, const float* __restrict__ a5,
    const float* __restrict__ a6, const float* __restrict__ a7, const float* __restrict__ a8,
    const float* __restrict__ a9, const float* __restrict__ a10, const float* __restrict__ a11,
    const unsigned* __restrict__ maxes,
    float* __restrict__ out_h, float* __restrict__ out_c)
{
    // double-buffered B tiles: [buf][mat][n=64][k=64 pad 72] bf16 -> 72 KB
    // rows 144B (16B-aligned); b128 read bank-quads = (c+g) mod 8 -> uniform (conflict-free)
    // u16 write banks = 4c + 2wv + (g>>1) -> <=4-way with same-dword pairing
    __shared__ __hip_bfloat16 Bsm[2][4][64][72];

    int tid = threadIdx.x;
    int lane = tid & 63, wv = tid >> 6;          // 16 waves
    int nb = blockIdx.x & 7;                     // batch -> XCD round-robin
    int cb = blockIdx.x >> 3;                    // 32 column-blocks of 16 HID cols

    const float* wih_b = w_ih + nb * KDIM * GDIM;
    const float* whh_b = w_hh + nb * KDIM * GDIM;
    const float* nih_b = n_ih + nb * KDIM * GDIM;
    const float* nhh_b = n_hh + nb * KDIM * GDIM;
    const __hip_bfloat16* xq_b = xqh + nb * BROWS * KDIM;
    const __hip_bfloat16* hh_b = hxh + nb * BROWS * KDIM;
    const __hip_bfloat16* hl_b = hxl + nb * BROWS * KDIM;

    float c_ih = fdec(maxes[0]);
    float c_hh = fdec(maxes[1]);

    f32x4 acc[4] = {};                           // one 16-row m-frag x 4 gate-frags

    int lh = lane & 15;
    int g  = lane >> 4;                          // 0..3
    int arow = (wv << 4) + lh;                   // this wave's 16 rows

    // staging mapping: thread -> one column c (per gate), k-row kk
    int c  = tid & 15;                           // col within gate-stripe
    int kk = tid >> 4;                           // 0..63 k within KSTEP

    float rw1a[4], rz1a[4], rw2a[4], rz2a[4];
    float rw1b[4], rz1b[4], rw2b[4], rz2b[4];

#define STAGE(R1, Z1, R2, Z2, K0) {                          \
    int base = ((K0) + kk) * GDIM + (cb << 4) + c;           \
    _Pragma("unroll")                                        \
    for (int nf = 0; nf < 4; ++nf) {                         \
        int gx = base + (nf << 9);                           \
        R1[nf] = wih_b[gx]; Z1[nf] = nih_b[gx];              \
        R2[nf] = whh_b[gx]; Z2[nf] = nhh_b[gx];              \
    } }

#define CVT(P, R1, Z1, R2, Z2) {                             \
    _Pragma("unroll")                                        \
    for (int nf = 0; nf < 4; ++nf) {                         \
        int n = (nf << 4) + c;                               \
        float w1 = R1[nf], z1 = Z1[nf];                      \
        float wq1 = rintf(fminf(fmaxf(w1, -0.9921875f), 0.9921875f) * 128.f) * 0.0078125f; \
        float e1 = wq1 + (z1 * c_ih) * 0.05f;                \
        __hip_bfloat16 h1 = __float2bfloat16(e1);            \
        Bsm[P][0][n][kk] = h1;                               \
        Bsm[P][1][n][kk] = __float2bfloat16(e1 - __bfloat162float(h1)); \
        float w2 = R2[nf], z2 = Z2[nf];                      \
        float wq2 = rintf(fminf(fmaxf(w2, -0.9921875f), 0.9921875f) * 128.f) * 0.0078125f; \
        float e2 = wq2 + (z2 * c_hh) * 0.05f;                \
        __hip_bfloat16 h2 = __float2bfloat16(e2);            \
        Bsm[P][2][n][kk] = h2;                               \
        Bsm[P][3][n][kk] = __float2bfloat16(e2 - __bfloat162float(h2)); \
    } }

#define COMPUTE(P, K0) {                                     \
    _Pragma("unroll")                                        \
    for (int kf = 0; kf < 2; ++kf) {                         \
        int ko = (K0) + (kf << 5) + (g << 3);                \
        int kb = (kf << 5) + (g << 3);                       \
        bf16x8 ax = *(const bf16x8*)(xq_b + arow * KDIM + ko); \
        bf16x8 ah = *(const bf16x8*)(hh_b + arow * KDIM + ko); \
        bf16x8 al = *(const bf16x8*)(hl_b + arow * KDIM + ko); \
        _Pragma("unroll")                                    \
        for (int nf = 0; nf < 4; ++nf) {                     \
            int n = (nf << 4) + lh;                          \
            bf16x8 b0 = *(const bf16x8*)&Bsm[P][0][n][kb];   \
            bf16x8 b1 = *(const bf16x8*)&Bsm[P][1][n][kb];   \
            bf16x8 b2 = *(const bf16x8*)&Bsm[P][2][n][kb];   \
            bf16x8 b3 = *(const bf16x8*)&Bsm[P][3][n][kb];   \
            acc[nf] = __builtin_amdgcn_mfma_f32_16x16x32_bf16(ax, b0, acc[nf], 0, 0, 0); \
            acc[nf] = __builtin_amdgcn_mfma_f32_16x16x32_bf16(ax, b1, acc[nf], 0, 0, 0); \
            acc[nf] = __builtin_amdgcn_mfma_f32_16x16x32_bf16(ah, b2, acc[nf], 0, 0, 0); \
            acc[nf] = __builtin_amdgcn_mfma_f32_16x16x32_bf16(ah, b3, acc[nf], 0, 0, 0); \
            acc[nf] = __builtin_amdgcn_mfma_f32_16x16x32_bf16(al, b2, acc[nf], 0, 0, 0); \
        } \
    } }

    // prologue: depth-2 register staging
    STAGE(rw1a, rz1a, rw2a, rz2a, 0);
    STAGE(rw1b, rz1b, rw2b, rz2b, KSTEP);

    for (int it = 0; it < NIT; it += 2) {
        // even iter -> buffer 0, set A
        CVT(0, rw1a, rz1a, rw2a, rz2a);
        if (it + 2 < NIT) STAGE(rw1a, rz1a, rw2a, rz2a, (it + 2) * KSTEP);
        __syncthreads();
        COMPUTE(0, it * KSTEP);
        // odd iter -> buffer 1, set B
        CVT(1, rw1b, rz1b, rw2b, rz2b);
        if (it + 3 < NIT) STAGE(rw1b, rz1b, rw2b, rz2b, (it + 3) * KSTEP);
        __syncthreads();
        COMPUTE(1, (it + 1) * KSTEP);
    }

    // fused epilogue: nf == gate index (i,j,f,o); all gates in-lane
    int hcol = (cb << 4) + lh;
    float A3 = a3[nb], A4 = a4[nb], A5 = a5[nb], A6 = a6[nb], A7 = a7[nb];
    float A8 = a8[nb], A9 = a9[nb], A10 = a10[nb], A11 = a11[nb];
    float bc_i = bias_comb[nb * GDIM + hcol];
    float bc_j = bias_comb[nb * GDIM + 512 + hcol];
    float bc_f = bias_comb[nb * GDIM + 1024 + hcol];
    float bc_o = bias_comb[nb * GDIM + 1536 + hcol];
    #pragma unroll
    for (int rg = 0; rg < 4; ++rg) {
        int r = (wv << 4) + (g << 2) + rg;
        float gi = acc[0][rg] + bc_i;
        float gj = acc[1][rg] + bc_j;
        float gf = acc[2][rg] + bc_f;
        float go = acc[3][rg] + bc_o;
        float fg = qpact(sigmf(gf), A3);
        float ig = qpact(sigmf(gi), A4);
        float act = qpact(tanhf(gj), A5);
        float og = qpact(sigmf(go), A6);
        int oidx = (nb * BROWS + r) * HIDD + hcol;
        float cv = cx[oidx];
        float gated = qpact(cv * fg, A7);
        float actin = qpact(ig * act, A8);
        float ncv = qpact(gated + actin, A9);
        float acv = qpact(tanhf(ncv), A10);
        float nhv = qpact(acv * og, A11);
        out_h[oidx] = nhv;
        out_c[oidx] = ncv;
    }
}

extern "C" void kernel_launch(void* const* d_in, const int* in_sizes, int n_in,
                              void* d_out, int out_size, void* d_ws, size_t ws_size,
                              hipStream_t stream) {
    const float* input = (const float*)d_in[0];
    const float* hx    = (const float*)d_in[1];
    const float* cx    = (const float*)d_in[2];
    const float* w_ih  = (const float*)d_in[3];
    const float* w_hh  = (const float*)d_in[4];
    const float* b_ih  = (const float*)d_in[5];
    const float* b_hh  = (const float*)d_in[6];
    const float* n_wih = (const float*)d_in[7];
    const float* n_whh = (const float*)d_in[8];
    const float* n_bih = (const float*)d_in[9];
    const float* n_bhh = (const float*)d_in[10];
    const float* a1  = (const float*)d_in[11];
    const float* a3  = (const float*)d_in[12];
    const float* a4  = (const float*)d_in[13];
    const float* a5  = (const float*)d_in[14];
    const float* a6  = (const float*)d_in[15];
    const float* a7  = (const float*)d_in[16];
    const float* a8  = (const float*)d_in[17];
    const float* a9  = (const float*)d_in[18];
    const float* a10 = (const float*)d_in[19];
    const float* a11 = (const float*)d_in[20];

    float* out_h = (float*)d_out;
    float* out_c = out_h + NBATCH * BROWS * HIDD;

    char* ws = (char*)d_ws;
    unsigned* maxes = (unsigned*)ws;
    __hip_bfloat16* xqh = (__hip_bfloat16*)(ws + 256);
    __hip_bfloat16* hxh = (__hip_bfloat16*)(ws + 256 + 2097152);
    __hip_bfloat16* hxl = (__hip_bfloat16*)(ws + 256 + 2 * 2097152);
    float* bias_comb    = (float*)(ws + 256 + 3 * 2097152);

    k_init<<<1, 64, 0, stream>>>(maxes);
    k_max<<<dim3(256, 4), 256, 0, stream>>>(w_ih, w_hh, b_ih, b_hh, maxes);
    k_prep<<<2048, 256, 0, stream>>>(input, hx, b_ih, b_hh, n_bih, n_bhh, a1, maxes,
                                     xqh, hxh, hxl, bias_comb);
    k_gemm<<<NBATCH * 32, 1024, 0, stream>>>(w_ih, w_hh, n_wih, n_whh, xqh, hxh, hxl,
                                             bias_comb, cx,
                                             a3, a4, a5, a6, a7, a8, a9, a10, a11,
                                             maxes, out_h, out_c);
}